// Round 6
// baseline (827.366 us; speedup 1.0000x reference)
//
#include <hip/hip_runtime.h>
#include <cstdint>
#include <cstddef>

#define NT 256
#define DFEAT 128
#define SCAN_ELEMS 1024
#define FB_T 192        // fused kernel: 3 waves = 6 gather-groups of 32
#define FB_NODES 96     // nodes per fused block (3 waves x 32 rows)
#define ASTRIDE 264     // ushorts per LDS agg row (528B -> 4-bank shift/row = 2-way, free)

typedef __attribute__((ext_vector_type(8))) short s8v;
typedef __attribute__((ext_vector_type(4))) float f32x4;

__device__ inline ushort f2bf(float f) {           // RNE fp32 -> bf16
  uint32_t u = __float_as_uint(f);
  u += 0x7fffu + ((u >> 16) & 1u);
  return (ushort)(u >> 16);
}
__device__ inline void wacc_bf4(uint2 v, float w, float& a0, float& a1, float& a2, float& a3) {
  a0 = fmaf(w, __uint_as_float(v.x << 16), a0);
  a1 = fmaf(w, __uint_as_float(v.x & 0xffff0000u), a1);
  a2 = fmaf(w, __uint_as_float(v.y << 16), a2);
  a3 = fmaf(w, __uint_as_float(v.y & 0xffff0000u), a3);
}

// ---------- zero int array ----------
__global__ void zero_k(int* __restrict__ p, int n) {
  int i = blockIdx.x * NT + threadIdx.x;
  if (i < n) p[i] = 0;
}

// ---------- histogram of dst, both graphs ----------
__global__ void hist2_k(const int* __restrict__ e_dst, int E,
                        const int* __restrict__ c_dst, int EC,
                        int* __restrict__ cnt_c, int* __restrict__ cnt_t) {
  int i = blockIdx.x * NT + threadIdx.x;
  if (i < E) atomicAdd(&cnt_c[e_dst[i]], 1);
  else if (i < E + EC) atomicAdd(&cnt_t[c_dst[i - E]], 1);
}

// ---------- scan pass A ----------
__global__ __launch_bounds__(NT) void scan_partial_k(
    const int* __restrict__ cnt_c, const int* __restrict__ cnt_t, int n,
    int* __restrict__ bsum, int nb_c) {
  int isT = blockIdx.x >= nb_c;
  const int* cnt = isT ? cnt_t : cnt_c;
  int b = isT ? blockIdx.x - nb_c : blockIdx.x;
  int base = b * SCAN_ELEMS + threadIdx.x * 4;

  int s = 0;
  if (base + 3 < n) {
    int4 v = *(const int4*)&cnt[base];
    s = v.x + v.y + v.z + v.w;
  } else {
    for (int j = 0; j < 4; j++) if (base + j < n) s += cnt[base + j];
  }
  for (int off = 32; off > 0; off >>= 1) s += __shfl_down(s, off, 64);
  __shared__ int ws[4];
  int lane = threadIdx.x & 63, w = threadIdx.x >> 6;
  if (lane == 0) ws[w] = s;
  __syncthreads();
  if (threadIdx.x == 0) bsum[blockIdx.x] = ws[0] + ws[1] + ws[2] + ws[3];
}

// ---------- scan pass B ----------
__global__ __launch_bounds__(NT) void scan_offsets_k(
    int* __restrict__ bsum, int nb_c, int nb_t,
    int* __restrict__ rp_c, int* __restrict__ rp_t, int n) {
  int seg_off = (blockIdx.x == 0) ? 0 : nb_c;
  int nb = (blockIdx.x == 0) ? nb_c : nb_t;
  int* rp = (blockIdx.x == 0) ? rp_c : rp_t;

  __shared__ int ls[NT];
  int t = threadIdx.x;
  int v = (t < nb) ? bsum[seg_off + t] : 0;
  ls[t] = v;
  __syncthreads();
  for (int off = 1; off < NT; off <<= 1) {
    int u = (t >= off) ? ls[t - off] : 0;
    __syncthreads();
    ls[t] += u;
    __syncthreads();
  }
  if (t < nb) bsum[seg_off + t] = ls[t] - v;
  if (t == nb - 1) rp[n] = ls[t];
}

// ---------- scan pass C: rowptr out; zeroes cnt (becomes fill cursor) ----------
__global__ __launch_bounds__(NT) void scan_final_k(
    int* __restrict__ cnt_c, int* __restrict__ cnt_t, int n,
    const int* __restrict__ bsum, int nb_c,
    int* __restrict__ rp_c, int* __restrict__ rp_t) {
  int isT = blockIdx.x >= nb_c;
  int* cnt = isT ? cnt_t : cnt_c;
  int* rp = isT ? rp_t : rp_c;
  int b = isT ? blockIdx.x - nb_c : blockIdx.x;
  int offset = bsum[blockIdx.x];
  int base = b * SCAN_ELEMS + threadIdx.x * 4;

  int4 v = make_int4(0, 0, 0, 0);
  if (base + 3 < n) v = *(const int4*)&cnt[base];
  else { if (base + 0 < n) v.x = cnt[base + 0];
         if (base + 1 < n) v.y = cnt[base + 1];
         if (base + 2 < n) v.z = cnt[base + 2];
         if (base + 3 < n) v.w = cnt[base + 3]; }
  int tsum = v.x + v.y + v.z + v.w;

  __shared__ int ls[NT];
  int t = threadIdx.x;
  ls[t] = tsum;
  __syncthreads();
  for (int off = 1; off < NT; off <<= 1) {
    int u = (t >= off) ? ls[t - off] : 0;
    __syncthreads();
    ls[t] += u;
    __syncthreads();
  }
  int excl = offset + ls[t] - tsum;

  int4 o;
  o.x = excl;
  o.y = o.x + v.x;
  o.z = o.y + v.y;
  o.w = o.z + v.z;
  if (base + 3 < n) {
    *(int4*)&rp[base] = o;
    *(int4*)&cnt[base] = make_int4(0, 0, 0, 0);
  } else {
    if (base + 0 < n) { rp[base + 0] = o.x; cnt[base + 0] = 0; }
    if (base + 1 < n) { rp[base + 1] = o.y; cnt[base + 1] = 0; }
    if (base + 2 < n) { rp[base + 2] = o.z; cnt[base + 2] = 0; }
    if (base + 3 < n) { rp[base + 3] = o.w; cnt[base + 3] = 0; }
  }
}

// ---------- dinv (needs rowptr only; runs BEFORE fill so fill can store weights) ----------
__global__ void dinv_k(const int* __restrict__ rp_c, float* __restrict__ dc,
                       const int* __restrict__ rp_t, float* __restrict__ dt, int n) {
  int i = blockIdx.x * NT + threadIdx.x;
  if (i < n) {
    dc[i] = rsqrtf((float)(rp_c[i + 1] - rp_c[i] + 1));
    dt[i] = rsqrtf((float)(rp_t[i + 1] - rp_t[i] + 1));
  }
}

// ---------- fill CSR + per-edge weight dinv[src], both graphs ----------
__global__ void fill2_k(const int* __restrict__ e_src, const int* __restrict__ e_dst, int E,
                        const int* __restrict__ c_src, const int* __restrict__ c_dst, int EC,
                        const int* __restrict__ rp_c, int* __restrict__ cur_c,
                        int* __restrict__ csr_c, float* __restrict__ csw_c,
                        const float* __restrict__ dinv_c,
                        const int* __restrict__ rp_t, int* __restrict__ cur_t,
                        int* __restrict__ csr_t, float* __restrict__ csw_t,
                        const float* __restrict__ dinv_t) {
  int i = blockIdx.x * NT + threadIdx.x;
  if (i < E) {
    int d = e_dst[i], s = e_src[i];
    int pos = rp_c[d] + atomicAdd(&cur_c[d], 1);
    csr_c[pos] = s;
    csw_c[pos] = dinv_c[s];
  } else if (i < E + EC) {
    int j = i - E;
    int d = c_dst[j], s = c_src[j];
    int pos = rp_t[d] + atomicAdd(&cur_t[d], 1);
    csr_t[pos] = s;
    csw_t[pos] = dinv_t[s];
  }
}

// ---------- x fp32 -> bf16 ----------
__global__ void convx_k(const float* __restrict__ x, ushort* __restrict__ xh, int total4) {
  int i = blockIdx.x * NT + threadIdx.x;
  if (i < total4) {
    float4 v = ((const float4*)x)[i];
    ushort4 o;
    o.x = f2bf(v.x); o.y = f2bf(v.y); o.z = f2bf(v.z); o.w = f2bf(v.w);
    ((ushort4*)xh)[i] = o;
  }
}

// ---------- W fp32 [l][k][c] -> bf16 transposed wT[l][c][k] ----------
__global__ void convw_k(const float* __restrict__ Wc, const float* __restrict__ Wt,
                        ushort* __restrict__ wT) {
  int gid = blockIdx.x * NT + threadIdx.x;
  int l = gid >> 14, rem = gid & 16383;
  int c = rem >> 7, k = rem & 127;
  const float* W = (l < 4) ? (Wc + (size_t)l * 16384) : (Wt + (size_t)(l - 4) * 16384);
  wT[gid] = f2bf(W[k * DFEAT + c]);
}

// ---------- weighted gather: acc += sum w_e * x[src_e] ----------
__device__ inline void gatherw(const ushort* __restrict__ x, const int* __restrict__ rp,
                               const int* __restrict__ cs, const float* __restrict__ cw,
                               int node, int lane,
                               float& a0, float& a1, float& a2, float& a3) {
  int s0 = rp[node], s1 = rp[node + 1];
  for (int p = s0; p < s1; p += 32) {
    int mm = min(32, s1 - p);
    int sv = (lane < mm) ? cs[p + lane] : 0;
    float wv = (lane < mm) ? cw[p + lane] : 0.f;
    int k = 0;
    for (; k + 4 <= mm; k += 4) {
      int sA = __shfl(sv, k, 32),     sB = __shfl(sv, k + 1, 32);
      int sC = __shfl(sv, k + 2, 32), sD = __shfl(sv, k + 3, 32);
      float wA = __shfl(wv, k, 32),     wB = __shfl(wv, k + 1, 32);
      float wC = __shfl(wv, k + 2, 32), wD = __shfl(wv, k + 3, 32);
      uint2 vA = *(const uint2*)&x[(size_t)sA * DFEAT + lane * 4];
      uint2 vB = *(const uint2*)&x[(size_t)sB * DFEAT + lane * 4];
      uint2 vC = *(const uint2*)&x[(size_t)sC * DFEAT + lane * 4];
      uint2 vD = *(const uint2*)&x[(size_t)sD * DFEAT + lane * 4];
      wacc_bf4(vA, wA, a0, a1, a2, a3);
      wacc_bf4(vB, wB, a0, a1, a2, a3);
      wacc_bf4(vC, wC, a0, a1, a2, a3);
      wacc_bf4(vD, wD, a0, a1, a2, a3);
    }
    for (; k < mm; k++) {
      int s = __shfl(sv, k, 32);
      float w = __shfl(wv, k, 32);
      wacc_bf4(*(const uint2*)&x[(size_t)s * DFEAT + lane * 4], w, a0, a1, a2, a3);
    }
  }
}

// ---------- fused layer: aggregate-first (both graphs) -> LDS -> dual MFMA GEMM ----------
// out = aggC @ Wc + aggT @ Wt + bc + bt  (+relu, bf16) ; last layer: fp32, no relu.
__global__ __launch_bounds__(FB_T) void fused_layer_k(
    const ushort* __restrict__ xin,
    const int* __restrict__ rp_c, const int* __restrict__ cs_c, const float* __restrict__ cw_c,
    const int* __restrict__ rp_t, const int* __restrict__ cs_t, const float* __restrict__ cw_t,
    const float* __restrict__ dinv_c, const float* __restrict__ dinv_t,
    const ushort* __restrict__ wTc, const ushort* __restrict__ wTt,
    const float* __restrict__ bc, const float* __restrict__ bt,
    ushort* __restrict__ xout, float* __restrict__ fout, int n, int last) {
  __shared__ __align__(16) ushort agg[FB_NODES * ASTRIDE];
  int tid = threadIdx.x;
  int g = tid >> 5, lane = tid & 31;
  int nbase = blockIdx.x * FB_NODES;

  // ---- phase 1: aggregate 96 nodes, 6 groups x 16 iterations ----
  for (int it = 0; it < 16; it++) {
    int nl = it * 6 + g;
    int node = nbase + nl;
    ushort* arow = &agg[nl * ASTRIDE];
    if (node < n) {
      float sc = dinv_c[node], st = dinv_t[node];
      uint2 selfv = *(const uint2*)&xin[(size_t)node * DFEAT + lane * 4];
      float f0 = __uint_as_float(selfv.x << 16);
      float f1 = __uint_as_float(selfv.x & 0xffff0000u);
      float f2 = __uint_as_float(selfv.y << 16);
      float f3 = __uint_as_float(selfv.y & 0xffff0000u);
      float a0 = sc * f0, a1 = sc * f1, a2 = sc * f2, a3 = sc * f3;   // self (conv)
      float b0 = st * f0, b1 = st * f1, b2 = st * f2, b3 = st * f3;   // self (ctrl)
      gatherw(xin, rp_c, cs_c, cw_c, node, lane, a0, a1, a2, a3);
      gatherw(xin, rp_t, cs_t, cw_t, node, lane, b0, b1, b2, b3);
      ushort4 hc, ht;
      hc.x = f2bf(sc * a0); hc.y = f2bf(sc * a1); hc.z = f2bf(sc * a2); hc.w = f2bf(sc * a3);
      ht.x = f2bf(st * b0); ht.y = f2bf(st * b1); ht.z = f2bf(st * b2); ht.w = f2bf(st * b3);
      *(ushort4*)&arow[lane * 4] = hc;
      *(ushort4*)&arow[DFEAT + lane * 4] = ht;
    } else {
      ushort4 z = {0, 0, 0, 0};
      *(ushort4*)&arow[lane * 4] = z;
      *(ushort4*)&arow[DFEAT + lane * 4] = z;
    }
  }
  __syncthreads();

  // ---- phase 2: dual GEMM from LDS A-frags, global W^T B-frags ----
  int wave = tid >> 6;            // 0..2, 32 rows each
  int l64 = tid & 63, m = l64 & 15, q = l64 >> 4;
  f32x4 zero4 = {0.f, 0.f, 0.f, 0.f};
  f32x4 acc[2][8];
#pragma unroll
  for (int s = 0; s < 2; s++)
#pragma unroll
    for (int c8 = 0; c8 < 8; c8++) acc[s][c8] = zero4;

#pragma unroll
  for (int ks = 0; ks < 4; ks++) {
    int ao = ks * 32 + q * 8;
    s8v aC0 = *(const s8v*)&agg[(wave * 32 + m) * ASTRIDE + ao];
    s8v aC1 = *(const s8v*)&agg[(wave * 32 + 16 + m) * ASTRIDE + ao];
    s8v aT0 = *(const s8v*)&agg[(wave * 32 + m) * ASTRIDE + DFEAT + ao];
    s8v aT1 = *(const s8v*)&agg[(wave * 32 + 16 + m) * ASTRIDE + DFEAT + ao];
#pragma unroll
    for (int c8 = 0; c8 < 8; c8++) {
      s8v bC = *(const s8v*)&wTc[(size_t)(c8 * 16 + m) * DFEAT + ao];
      s8v bT = *(const s8v*)&wTt[(size_t)(c8 * 16 + m) * DFEAT + ao];
      acc[0][c8] = __builtin_amdgcn_mfma_f32_16x16x32_bf16(aC0, bC, acc[0][c8], 0, 0, 0);
      acc[0][c8] = __builtin_amdgcn_mfma_f32_16x16x32_bf16(aT0, bT, acc[0][c8], 0, 0, 0);
      acc[1][c8] = __builtin_amdgcn_mfma_f32_16x16x32_bf16(aC1, bC, acc[1][c8], 0, 0, 0);
      acc[1][c8] = __builtin_amdgcn_mfma_f32_16x16x32_bf16(aT1, bT, acc[1][c8], 0, 0, 0);
    }
  }

  float bsv[8];
#pragma unroll
  for (int c8 = 0; c8 < 8; c8++) bsv[c8] = bc[c8 * 16 + m] + bt[c8 * 16 + m];

#pragma unroll
  for (int sub = 0; sub < 2; sub++) {
#pragma unroll
    for (int r = 0; r < 4; r++) {
      int orow = nbase + wave * 32 + sub * 16 + q * 4 + r;
      if (orow < n) {
#pragma unroll
        for (int c8 = 0; c8 < 8; c8++) {
          int col = c8 * 16 + m;
          float v = acc[sub][c8][r] + bsv[c8];
          if (last) fout[(size_t)orow * DFEAT + col] = v;
          else      xout[(size_t)orow * DFEAT + col] = f2bf(fmaxf(v, 0.f));
        }
      }
    }
  }
}

extern "C" void kernel_launch(void* const* d_in, const int* in_sizes, int n_in,
                              void* d_out, int out_size, void* d_ws, size_t ws_size,
                              hipStream_t stream) {
  const float* x0 = (const float*)d_in[0];
  const int*   ei = (const int*)d_in[1];
  const int*   ci = (const int*)d_in[2];
  const float* Wc = (const float*)d_in[3];
  const float* bc = (const float*)d_in[4];
  const float* Wt = (const float*)d_in[5];
  const float* bt = (const float*)d_in[6];
  float* out = (float*)d_out;

  int n  = in_sizes[0] / DFEAT;     // 100000
  int E  = in_sizes[1] / 2;         // 600000
  int EC = in_sizes[2] / 2;         // 200000

  const int* e_src = ei;
  const int* e_dst = ei + E;
  const int* c_src = ci;
  const int* c_dst = ci + EC;

  char* p = (char*)d_ws;
  ushort* xh0 = (ushort*)p; p += (size_t)n * DFEAT * 2;
  ushort* xh1 = (ushort*)p; p += (size_t)n * DFEAT * 2;
  ushort* wT  = (ushort*)p; p += (size_t)8 * DFEAT * DFEAT * 2;
  float* dinv_c = (float*)p; p += (size_t)n * 4;
  float* dinv_t = (float*)p; p += (size_t)n * 4;
  float* csw_c  = (float*)p; p += (size_t)E * 4;
  float* csw_t  = (float*)p; p += (size_t)EC * 4;
  int* cnt_c = (int*)p; p += (size_t)n * 4;
  int* cnt_t = (int*)p; p += (size_t)n * 4;
  int* rp_c  = (int*)p; p += (size_t)(n + 1) * 4;
  int* rp_t  = (int*)p; p += (size_t)(n + 1) * 4;
  int* csr_c = (int*)p; p += (size_t)E * 4;
  int* csr_t = (int*)p; p += (size_t)EC * 4;
  int* bsum  = (int*)p;

  int nb_n    = (n + NT - 1) / NT;
  int nb_scan = (n + SCAN_ELEMS - 1) / SCAN_ELEMS;
  int nb_fuse = (n + FB_NODES - 1) / FB_NODES;

  // ---- build CSR (+edge weights) + dinv once per launch ----
  zero_k<<<(2 * n + NT - 1) / NT, NT, 0, stream>>>(cnt_c, 2 * n);
  hist2_k<<<(E + EC + NT - 1) / NT, NT, 0, stream>>>(e_dst, E, c_dst, EC, cnt_c, cnt_t);
  scan_partial_k<<<2 * nb_scan, NT, 0, stream>>>(cnt_c, cnt_t, n, bsum, nb_scan);
  scan_offsets_k<<<2, NT, 0, stream>>>(bsum, nb_scan, nb_scan, rp_c, rp_t, n);
  scan_final_k<<<2 * nb_scan, NT, 0, stream>>>(cnt_c, cnt_t, n, bsum, nb_scan, rp_c, rp_t);
  dinv_k<<<nb_n, NT, 0, stream>>>(rp_c, dinv_c, rp_t, dinv_t, n);
  fill2_k<<<(E + EC + NT - 1) / NT, NT, 0, stream>>>(e_src, e_dst, E, c_src, c_dst, EC,
                                                     rp_c, cnt_c, csr_c, csw_c, dinv_c,
                                                     rp_t, cnt_t, csr_t, csw_t, dinv_t);

  // ---- bf16 conversions ----
  convx_k<<<(n * 32 + NT - 1) / NT, NT, 0, stream>>>(x0, xh0, n * 32);
  convw_k<<<(8 * DFEAT * DFEAT) / NT, NT, 0, stream>>>(Wc, Wt, wT);

  // ---- layers (ping-pong xh0/xh1) ----
  for (int i = 0; i < 4; i++) {
    const ushort* xin = (i & 1) ? xh1 : xh0;
    ushort* xout = (i & 1) ? xh0 : xh1;
    fused_layer_k<<<nb_fuse, FB_T, 0, stream>>>(
        xin, rp_c, csr_c, csw_c, rp_t, csr_t, csw_t, dinv_c, dinv_t,
        wT + (size_t)i * DFEAT * DFEAT, wT + (size_t)(4 + i) * DFEAT * DFEAT,
        bc + i * DFEAT, bt + i * DFEAT,
        xout, out, n, (i == 3) ? 1 : 0);
  }
}

// Round 7
// 572.906 us; speedup vs baseline: 1.4442x; 1.4442x over previous
//
#include <hip/hip_runtime.h>
#include <cstdint>
#include <cstddef>

#define NT 256
#define DFEAT 128
#define SCAN_ELEMS 1024
#define GB_ROWS 128     // rows per gemm block (4 waves x 32 rows)

typedef __attribute__((ext_vector_type(8))) short s8v;
typedef __attribute__((ext_vector_type(4))) float f32x4;

__device__ inline ushort f2bf(float f) {           // RNE fp32 -> bf16
  uint32_t u = __float_as_uint(f);
  u += 0x7fffu + ((u >> 16) & 1u);
  return (ushort)(u >> 16);
}
__device__ inline void wacc_bf4(uint2 v, float w, float& a0, float& a1, float& a2, float& a3) {
  a0 = fmaf(w, __uint_as_float(v.x << 16), a0);
  a1 = fmaf(w, __uint_as_float(v.x & 0xffff0000u), a1);
  a2 = fmaf(w, __uint_as_float(v.y << 16), a2);
  a3 = fmaf(w, __uint_as_float(v.y & 0xffff0000u), a3);
}

// ---------- zero int array ----------
__global__ void zero_k(int* __restrict__ p, int n) {
  int i = blockIdx.x * NT + threadIdx.x;
  if (i < n) p[i] = 0;
}

// ---------- histogram of dst, both graphs ----------
__global__ void hist2_k(const int* __restrict__ e_dst, int E,
                        const int* __restrict__ c_dst, int EC,
                        int* __restrict__ cnt_c, int* __restrict__ cnt_t) {
  int i = blockIdx.x * NT + threadIdx.x;
  if (i < E) atomicAdd(&cnt_c[e_dst[i]], 1);
  else if (i < E + EC) atomicAdd(&cnt_t[c_dst[i - E]], 1);
}

// ---------- scan pass A ----------
__global__ __launch_bounds__(NT) void scan_partial_k(
    const int* __restrict__ cnt_c, const int* __restrict__ cnt_t, int n,
    int* __restrict__ bsum, int nb_c) {
  int isT = blockIdx.x >= nb_c;
  const int* cnt = isT ? cnt_t : cnt_c;
  int b = isT ? blockIdx.x - nb_c : blockIdx.x;
  int base = b * SCAN_ELEMS + threadIdx.x * 4;

  int s = 0;
  if (base + 3 < n) {
    int4 v = *(const int4*)&cnt[base];
    s = v.x + v.y + v.z + v.w;
  } else {
    for (int j = 0; j < 4; j++) if (base + j < n) s += cnt[base + j];
  }
  for (int off = 32; off > 0; off >>= 1) s += __shfl_down(s, off, 64);
  __shared__ int ws[4];
  int lane = threadIdx.x & 63, w = threadIdx.x >> 6;
  if (lane == 0) ws[w] = s;
  __syncthreads();
  if (threadIdx.x == 0) bsum[blockIdx.x] = ws[0] + ws[1] + ws[2] + ws[3];
}

// ---------- scan pass B ----------
__global__ __launch_bounds__(NT) void scan_offsets_k(
    int* __restrict__ bsum, int nb_c, int nb_t,
    int* __restrict__ rp_c, int* __restrict__ rp_t, int n) {
  int seg_off = (blockIdx.x == 0) ? 0 : nb_c;
  int nb = (blockIdx.x == 0) ? nb_c : nb_t;
  int* rp = (blockIdx.x == 0) ? rp_c : rp_t;

  __shared__ int ls[NT];
  int t = threadIdx.x;
  int v = (t < nb) ? bsum[seg_off + t] : 0;
  ls[t] = v;
  __syncthreads();
  for (int off = 1; off < NT; off <<= 1) {
    int u = (t >= off) ? ls[t - off] : 0;
    __syncthreads();
    ls[t] += u;
    __syncthreads();
  }
  if (t < nb) bsum[seg_off + t] = ls[t] - v;
  if (t == nb - 1) rp[n] = ls[t];
}

// ---------- scan pass C: rowptr out; zeroes cnt (becomes fill cursor) ----------
__global__ __launch_bounds__(NT) void scan_final_k(
    int* __restrict__ cnt_c, int* __restrict__ cnt_t, int n,
    const int* __restrict__ bsum, int nb_c,
    int* __restrict__ rp_c, int* __restrict__ rp_t) {
  int isT = blockIdx.x >= nb_c;
  int* cnt = isT ? cnt_t : cnt_c;
  int* rp = isT ? rp_t : rp_c;
  int b = isT ? blockIdx.x - nb_c : blockIdx.x;
  int offset = bsum[blockIdx.x];
  int base = b * SCAN_ELEMS + threadIdx.x * 4;

  int4 v = make_int4(0, 0, 0, 0);
  if (base + 3 < n) v = *(const int4*)&cnt[base];
  else { if (base + 0 < n) v.x = cnt[base + 0];
         if (base + 1 < n) v.y = cnt[base + 1];
         if (base + 2 < n) v.z = cnt[base + 2];
         if (base + 3 < n) v.w = cnt[base + 3]; }
  int tsum = v.x + v.y + v.z + v.w;

  __shared__ int ls[NT];
  int t = threadIdx.x;
  ls[t] = tsum;
  __syncthreads();
  for (int off = 1; off < NT; off <<= 1) {
    int u = (t >= off) ? ls[t - off] : 0;
    __syncthreads();
    ls[t] += u;
    __syncthreads();
  }
  int excl = offset + ls[t] - tsum;

  int4 o;
  o.x = excl;
  o.y = o.x + v.x;
  o.z = o.y + v.y;
  o.w = o.z + v.z;
  if (base + 3 < n) {
    *(int4*)&rp[base] = o;
    *(int4*)&cnt[base] = make_int4(0, 0, 0, 0);
  } else {
    if (base + 0 < n) { rp[base + 0] = o.x; cnt[base + 0] = 0; }
    if (base + 1 < n) { rp[base + 1] = o.y; cnt[base + 1] = 0; }
    if (base + 2 < n) { rp[base + 2] = o.z; cnt[base + 2] = 0; }
    if (base + 3 < n) { rp[base + 3] = o.w; cnt[base + 3] = 0; }
  }
}

// ---------- dinv (runs BEFORE fill so fill can store per-edge weights) ----------
__global__ void dinv_k(const int* __restrict__ rp_c, float* __restrict__ dc,
                       const int* __restrict__ rp_t, float* __restrict__ dt, int n) {
  int i = blockIdx.x * NT + threadIdx.x;
  if (i < n) {
    dc[i] = rsqrtf((float)(rp_c[i + 1] - rp_c[i] + 1));
    dt[i] = rsqrtf((float)(rp_t[i + 1] - rp_t[i] + 1));
  }
}

// ---------- fill CSR + per-edge weight dinv[src], both graphs ----------
__global__ void fill2_k(const int* __restrict__ e_src, const int* __restrict__ e_dst, int E,
                        const int* __restrict__ c_src, const int* __restrict__ c_dst, int EC,
                        const int* __restrict__ rp_c, int* __restrict__ cur_c,
                        int* __restrict__ csr_c, float* __restrict__ csw_c,
                        const float* __restrict__ dinv_c,
                        const int* __restrict__ rp_t, int* __restrict__ cur_t,
                        int* __restrict__ csr_t, float* __restrict__ csw_t,
                        const float* __restrict__ dinv_t) {
  int i = blockIdx.x * NT + threadIdx.x;
  if (i < E) {
    int d = e_dst[i], s = e_src[i];
    int pos = rp_c[d] + atomicAdd(&cur_c[d], 1);
    csr_c[pos] = s;
    csw_c[pos] = dinv_c[s];
  } else if (i < E + EC) {
    int j = i - E;
    int d = c_dst[j], s = c_src[j];
    int pos = rp_t[d] + atomicAdd(&cur_t[d], 1);
    csr_t[pos] = s;
    csw_t[pos] = dinv_t[s];
  }
}

// ---------- x fp32 -> bf16 ----------
__global__ void convx_k(const float* __restrict__ x, ushort* __restrict__ xh, int total4) {
  int i = blockIdx.x * NT + threadIdx.x;
  if (i < total4) {
    float4 v = ((const float4*)x)[i];
    ushort4 o;
    o.x = f2bf(v.x); o.y = f2bf(v.y); o.z = f2bf(v.z); o.w = f2bf(v.w);
    ((ushort4*)xh)[i] = o;
  }
}

// ---------- W fp32 [l][k][c] -> bf16 transposed wT[l][c][k] ----------
__global__ void convw_k(const float* __restrict__ Wc, const float* __restrict__ Wt,
                        ushort* __restrict__ wT) {
  int gid = blockIdx.x * NT + threadIdx.x;
  int l = gid >> 14, rem = gid & 16383;
  int c = rem >> 7, k = rem & 127;
  const float* W = (l < 4) ? (Wc + (size_t)l * 16384) : (Wt + (size_t)(l - 4) * 16384);
  wT[gid] = f2bf(W[k * DFEAT + c]);
}

// ---------- weighted gather: acc += sum w_e * x[src_e] ----------
__device__ inline void gatherw(const ushort* __restrict__ x, const int* __restrict__ rp,
                               const int* __restrict__ cs, const float* __restrict__ cw,
                               int node, int lane,
                               float& a0, float& a1, float& a2, float& a3) {
  int s0 = rp[node], s1 = rp[node + 1];
  for (int p = s0; p < s1; p += 32) {
    int mm = min(32, s1 - p);
    int sv = (lane < mm) ? cs[p + lane] : 0;
    float wv = (lane < mm) ? cw[p + lane] : 0.f;
    int k = 0;
    for (; k + 4 <= mm; k += 4) {
      int sA = __shfl(sv, k, 32),     sB = __shfl(sv, k + 1, 32);
      int sC = __shfl(sv, k + 2, 32), sD = __shfl(sv, k + 3, 32);
      float wA = __shfl(wv, k, 32),     wB = __shfl(wv, k + 1, 32);
      float wC = __shfl(wv, k + 2, 32), wD = __shfl(wv, k + 3, 32);
      uint2 vA = *(const uint2*)&x[(size_t)sA * DFEAT + lane * 4];
      uint2 vB = *(const uint2*)&x[(size_t)sB * DFEAT + lane * 4];
      uint2 vC = *(const uint2*)&x[(size_t)sC * DFEAT + lane * 4];
      uint2 vD = *(const uint2*)&x[(size_t)sD * DFEAT + lane * 4];
      wacc_bf4(vA, wA, a0, a1, a2, a3);
      wacc_bf4(vB, wB, a0, a1, a2, a3);
      wacc_bf4(vC, wC, a0, a1, a2, a3);
      wacc_bf4(vD, wD, a0, a1, a2, a3);
    }
    for (; k < mm; k++) {
      int s = __shfl(sv, k, 32);
      float w = __shfl(wv, k, 32);
      wacc_bf4(*(const uint2*)&x[(size_t)s * DFEAT + lane * 4], w, a0, a1, a2, a3);
    }
  }
}

// ---------- aggregate-first: aggC/aggT = normalized gathers of xin (both graphs) ----------
// High-occupancy, no LDS, no barrier: 8 nodes/block, 32-lane group per node.
__global__ __launch_bounds__(256) void agg2_k(
    const ushort* __restrict__ xin,
    const int* __restrict__ rp_c, const int* __restrict__ cs_c, const float* __restrict__ cw_c,
    const int* __restrict__ rp_t, const int* __restrict__ cs_t, const float* __restrict__ cw_t,
    const float* __restrict__ dinv_c, const float* __restrict__ dinv_t,
    ushort* __restrict__ aggC, ushort* __restrict__ aggT, int n) {
  int node = blockIdx.x * 8 + (threadIdx.x >> 5);
  if (node >= n) return;
  int lane = threadIdx.x & 31;

  float sc = dinv_c[node], st = dinv_t[node];
  uint2 selfv = *(const uint2*)&xin[(size_t)node * DFEAT + lane * 4];
  float f0 = __uint_as_float(selfv.x << 16);
  float f1 = __uint_as_float(selfv.x & 0xffff0000u);
  float f2 = __uint_as_float(selfv.y << 16);
  float f3 = __uint_as_float(selfv.y & 0xffff0000u);

  float a0 = sc * f0, a1 = sc * f1, a2 = sc * f2, a3 = sc * f3;   // self (conv)
  gatherw(xin, rp_c, cs_c, cw_c, node, lane, a0, a1, a2, a3);
  float b0 = st * f0, b1 = st * f1, b2 = st * f2, b3 = st * f3;   // self (ctrl)
  gatherw(xin, rp_t, cs_t, cw_t, node, lane, b0, b1, b2, b3);

  ushort4 hc, ht;
  hc.x = f2bf(sc * a0); hc.y = f2bf(sc * a1); hc.z = f2bf(sc * a2); hc.w = f2bf(sc * a3);
  ht.x = f2bf(st * b0); ht.y = f2bf(st * b1); ht.z = f2bf(st * b2); ht.w = f2bf(st * b3);
  *(ushort4*)&aggC[(size_t)node * DFEAT + lane * 4] = hc;
  *(ushort4*)&aggT[(size_t)node * DFEAT + lane * 4] = ht;
}

// ---------- post GEMM: out = aggC@Wc + aggT@Wt + bc + bt (+relu / fp32 last) ----------
// No LDS, no barrier. B-frags straight from global (weights are L1/L2-hot).
__global__ __launch_bounds__(256) void gemm_post_k(
    const ushort* __restrict__ aggC, const ushort* __restrict__ aggT,
    const ushort* __restrict__ wTc, const ushort* __restrict__ wTt,
    const float* __restrict__ bc, const float* __restrict__ bt,
    ushort* __restrict__ xout, float* __restrict__ fout, int n, int last) {
  int tid = threadIdx.x;
  int wave = tid >> 6, l64 = tid & 63, m = l64 & 15, q = l64 >> 4;
  int row0 = blockIdx.x * GB_ROWS + wave * 32;
  int rowA = row0 + m;
  int rowB = row0 + 16 + m;

  f32x4 zero4 = {0.f, 0.f, 0.f, 0.f};
  f32x4 acc[2][8];
#pragma unroll
  for (int s = 0; s < 2; s++)
#pragma unroll
    for (int c8 = 0; c8 < 8; c8++) acc[s][c8] = zero4;

#pragma unroll
  for (int ks = 0; ks < 4; ks++) {
    int ao = ks * 32 + q * 8;
    uint4 zu = make_uint4(0, 0, 0, 0);
    union { uint4 u; s8v s; } aC0, aC1, aT0, aT1;
    aC0.u = (rowA < n) ? *(const uint4*)&aggC[(size_t)rowA * DFEAT + ao] : zu;
    aC1.u = (rowB < n) ? *(const uint4*)&aggC[(size_t)rowB * DFEAT + ao] : zu;
    aT0.u = (rowA < n) ? *(const uint4*)&aggT[(size_t)rowA * DFEAT + ao] : zu;
    aT1.u = (rowB < n) ? *(const uint4*)&aggT[(size_t)rowB * DFEAT + ao] : zu;
#pragma unroll
    for (int c8 = 0; c8 < 8; c8++) {
      s8v bC = *(const s8v*)&wTc[(size_t)(c8 * 16 + m) * DFEAT + ao];
      s8v bT = *(const s8v*)&wTt[(size_t)(c8 * 16 + m) * DFEAT + ao];
      acc[0][c8] = __builtin_amdgcn_mfma_f32_16x16x32_bf16(aC0.s, bC, acc[0][c8], 0, 0, 0);
      acc[0][c8] = __builtin_amdgcn_mfma_f32_16x16x32_bf16(aT0.s, bT, acc[0][c8], 0, 0, 0);
      acc[1][c8] = __builtin_amdgcn_mfma_f32_16x16x32_bf16(aC1.s, bC, acc[1][c8], 0, 0, 0);
      acc[1][c8] = __builtin_amdgcn_mfma_f32_16x16x32_bf16(aT1.s, bT, acc[1][c8], 0, 0, 0);
    }
  }

  float bsv[8];
#pragma unroll
  for (int c8 = 0; c8 < 8; c8++) bsv[c8] = bc[c8 * 16 + m] + bt[c8 * 16 + m];

#pragma unroll
  for (int sub = 0; sub < 2; sub++) {
#pragma unroll
    for (int r = 0; r < 4; r++) {
      int orow = row0 + sub * 16 + q * 4 + r;
      if (orow < n) {
#pragma unroll
        for (int c8 = 0; c8 < 8; c8++) {
          int col = c8 * 16 + m;
          float v = acc[sub][c8][r] + bsv[c8];
          if (last) fout[(size_t)orow * DFEAT + col] = v;
          else      xout[(size_t)orow * DFEAT + col] = f2bf(fmaxf(v, 0.f));
        }
      }
    }
  }
}

extern "C" void kernel_launch(void* const* d_in, const int* in_sizes, int n_in,
                              void* d_out, int out_size, void* d_ws, size_t ws_size,
                              hipStream_t stream) {
  const float* x0 = (const float*)d_in[0];
  const int*   ei = (const int*)d_in[1];
  const int*   ci = (const int*)d_in[2];
  const float* Wc = (const float*)d_in[3];
  const float* bc = (const float*)d_in[4];
  const float* Wt = (const float*)d_in[5];
  const float* bt = (const float*)d_in[6];
  float* out = (float*)d_out;

  int n  = in_sizes[0] / DFEAT;     // 100000
  int E  = in_sizes[1] / 2;         // 600000
  int EC = in_sizes[2] / 2;         // 200000

  const int* e_src = ei;
  const int* e_dst = ei + E;
  const int* c_src = ci;
  const int* c_dst = ci + EC;

  char* p = (char*)d_ws;
  ushort* xh0  = (ushort*)p; p += (size_t)n * DFEAT * 2;
  ushort* xh1  = (ushort*)p; p += (size_t)n * DFEAT * 2;
  ushort* aggC = (ushort*)p; p += (size_t)n * DFEAT * 2;
  ushort* aggT = (ushort*)p; p += (size_t)n * DFEAT * 2;
  ushort* wT   = (ushort*)p; p += (size_t)8 * DFEAT * DFEAT * 2;
  float* dinv_c = (float*)p; p += (size_t)n * 4;
  float* dinv_t = (float*)p; p += (size_t)n * 4;
  float* csw_c  = (float*)p; p += (size_t)E * 4;
  float* csw_t  = (float*)p; p += (size_t)EC * 4;
  int* cnt_c = (int*)p; p += (size_t)n * 4;
  int* cnt_t = (int*)p; p += (size_t)n * 4;
  int* rp_c  = (int*)p; p += (size_t)(n + 1) * 4;
  int* rp_t  = (int*)p; p += (size_t)(n + 1) * 4;
  int* csr_c = (int*)p; p += (size_t)E * 4;
  int* csr_t = (int*)p; p += (size_t)EC * 4;
  int* bsum  = (int*)p;

  int nb_n    = (n + NT - 1) / NT;
  int nb_node = (n + 7) / 8;
  int nb_gemm = (n + GB_ROWS - 1) / GB_ROWS;
  int nb_scan = (n + SCAN_ELEMS - 1) / SCAN_ELEMS;

  // ---- build CSR (+edge weights) + dinv once per launch ----
  zero_k<<<(2 * n + NT - 1) / NT, NT, 0, stream>>>(cnt_c, 2 * n);
  hist2_k<<<(E + EC + NT - 1) / NT, NT, 0, stream>>>(e_dst, E, c_dst, EC, cnt_c, cnt_t);
  scan_partial_k<<<2 * nb_scan, NT, 0, stream>>>(cnt_c, cnt_t, n, bsum, nb_scan);
  scan_offsets_k<<<2, NT, 0, stream>>>(bsum, nb_scan, nb_scan, rp_c, rp_t, n);
  scan_final_k<<<2 * nb_scan, NT, 0, stream>>>(cnt_c, cnt_t, n, bsum, nb_scan, rp_c, rp_t);
  dinv_k<<<nb_n, NT, 0, stream>>>(rp_c, dinv_c, rp_t, dinv_t, n);
  fill2_k<<<(E + EC + NT - 1) / NT, NT, 0, stream>>>(e_src, e_dst, E, c_src, c_dst, EC,
                                                     rp_c, cnt_c, csr_c, csw_c, dinv_c,
                                                     rp_t, cnt_t, csr_t, csw_t, dinv_t);

  // ---- bf16 conversions ----
  convx_k<<<(n * 32 + NT - 1) / NT, NT, 0, stream>>>(x0, xh0, n * 32);
  convw_k<<<(8 * DFEAT * DFEAT) / NT, NT, 0, stream>>>(Wc, Wt, wT);

  // ---- layers (ping-pong xh0/xh1) ----
  for (int i = 0; i < 4; i++) {
    const ushort* xin = (i & 1) ? xh1 : xh0;
    ushort* xout = (i & 1) ? xh0 : xh1;
    agg2_k<<<nb_node, NT, 0, stream>>>(xin, rp_c, csr_c, csw_c, rp_t, csr_t, csw_t,
                                       dinv_c, dinv_t, aggC, aggT, n);
    gemm_post_k<<<nb_gemm, NT, 0, stream>>>(aggC, aggT,
                                            wT + (size_t)i * DFEAT * DFEAT,
                                            wT + (size_t)(4 + i) * DFEAT * DFEAT,
                                            bc + i * DFEAT, bt + i * DFEAT,
                                            xout, out, n, (i == 3) ? 1 : 0);
  }
}